// Round 6
// baseline (107.567 us; speedup 1.0000x reference)
//
#include <hip/hip_runtime.h>

// (B,C,H,W)=(32,32,64,64), D=32, K=512
#define C_    32
#define D_    32
#define K_    512
#define HW_   4096
#define NTOK  131072
#define IDX_OFF   4194304
#define LOSS_OFF  4325376
#define TAU   2e-3f

// ws: cbn @0 (2 KB), cbh @4096 (32 KB), cbl @36864 (32 KB)
#define WS_CBN   0
#define WS_CBH   4096
#define WS_CBL   36864
#define WS_NEEDED 69632

typedef __attribute__((ext_vector_type(8))) __bf16 bf16x8;
typedef __attribute__((ext_vector_type(8))) short  short8;
typedef __attribute__((ext_vector_type(4))) float  f32x4;

__device__ inline unsigned short f2bf(float x) {          // RNE fp32->bf16
    unsigned u = __builtin_bit_cast(unsigned, x);
    return (unsigned short)((u + 0x7FFFu + ((u >> 16) & 1u)) >> 16);
}
__device__ inline float bf2f(unsigned short h) {
    unsigned u = ((unsigned)h) << 16; return __builtin_bit_cast(float, u);
}

// ---------- codebook split + norms (tiny, 2 blocks) ----------
__global__ __launch_bounds__(256)
void prep_cb(const float* __restrict__ cb, float* __restrict__ cbn,
             unsigned short* __restrict__ cbh, unsigned short* __restrict__ cbl)
{
    const int k = blockIdx.x * 256 + threadIdx.x;   // grid = 2 -> k in [0,512)
    const float* row = cb + k * D_;
    float s = 0.f;
    unsigned short h[32], lo[32];
    #pragma unroll
    for (int d = 0; d < D_; ++d) {
        const float v = row[d]; s = fmaf(v, v, s);
        const unsigned short hh = f2bf(v);
        h[d] = hh; lo[d] = f2bf(v - bf2f(hh));
    }
    cbn[k] = s;
    #pragma unroll
    for (int j = 0; j < 4; ++j) {
        *(short8*)(cbh + k * 32 + 8 * j) = *(const short8*)(h  + 8 * j);
        *(short8*)(cbl + k * 32 + 8 * j) = *(const short8*)(lo + 8 * j);
    }
}

// ---------- fully fused: conv -> MFMA scan -> rescan -> gather/loss/post-conv ----------
__global__ __launch_bounds__(256)
void vq_fused(const float* __restrict__ z,  const float* __restrict__ qw,
              const float* __restrict__ qb, const float* __restrict__ cb,
              const float* __restrict__ pw, const float* __restrict__ pb,
              const unsigned short* __restrict__ cbh, const unsigned short* __restrict__ cbl,
              const float* __restrict__ cbn, float* __restrict__ out)
{
    __shared__ float xsh[4][32][33];   // per-wave xf tile, padded
    __shared__ int   si[4][32];        // per-wave idx(+flag bit 9)
    __shared__ float lsum[4];

    const int tid = threadIdx.x;
    const int wv = tid >> 6, l = tid & 63;
    const int tok = l & 31, half = l >> 5;
    const int T0 = blockIdx.x * 128 + wv * 32;      // wave's 32-token tile
    const int b = T0 >> 12, hw0 = T0 & (HW_ - 1);

    // ---- phase 1: quant conv (2 lanes per token, 16 channels each) ----
    {
        const float* zbase = z + (size_t)b * (C_ * HW_) + hw0 + tok;
        float zv[C_];
        #pragma unroll
        for (int c = 0; c < C_; ++c) zv[c] = zbase[(size_t)c * HW_];
        #pragma unroll
        for (int i = 0; i < 16; ++i) {
            const int d = half * 16 + i;
            float a = qb[d];
            const float4* qr = (const float4*)(qw + d * C_);
            #pragma unroll
            for (int c4 = 0; c4 < 8; ++c4) {
                const float4 q4 = qr[c4];
                a = fmaf(zv[4*c4+0], q4.x, a); a = fmaf(zv[4*c4+1], q4.y, a);
                a = fmaf(zv[4*c4+2], q4.z, a); a = fmaf(zv[4*c4+3], q4.w, a);
            }
            xsh[wv][tok][d] = a;
        }
    }
    __syncthreads();

    // ---- A fragments (row=lane&15 token, k-chunk=(lane>>4)*8), bf16 hi/lo split ----
    const int lr = l & 15, lg = l >> 4;
    short8 sh0, sl0, sh1, sl1;
    #pragma unroll
    for (int j = 0; j < 8; ++j) {
        const float v0 = xsh[wv][lr][lg * 8 + j];
        const float v1 = xsh[wv][16 + lr][lg * 8 + j];
        const unsigned short a0 = f2bf(v0), a1 = f2bf(v1);
        sh0[j] = (short)a0; sl0[j] = (short)f2bf(v0 - bf2f(a0));
        sh1[j] = (short)a1; sl1[j] = (short)f2bf(v1 - bf2f(a1));
    }
    const bf16x8 ah0 = __builtin_bit_cast(bf16x8, sh0);
    const bf16x8 al0 = __builtin_bit_cast(bf16x8, sl0);
    const bf16x8 ah1 = __builtin_bit_cast(bf16x8, sh1);
    const bf16x8 al1 = __builtin_bit_cast(bf16x8, sl1);

    // ---- phase 2: split-bf16 MFMA top-2 scan over 512 codes ----
    float b1[8], b2[8]; int i1[8];
    #pragma unroll
    for (int s = 0; s < 8; ++s) { b1[s] = 3.4e38f; b2[s] = 3.4e38f; i1[s] = 0; }

    #pragma unroll 2
    for (int nt = 0; nt < 32; ++nt) {
        const size_t boff = (size_t)(nt * 16 + lr) * 32 + lg * 8;
        const bf16x8 bh = __builtin_bit_cast(bf16x8, *(const short8*)(cbh + boff));
        const bf16x8 bl = __builtin_bit_cast(bf16x8, *(const short8*)(cbl + boff));
        const float cn = cbn[nt * 16 + lr];
        f32x4 acc0 = {0.f,0.f,0.f,0.f}, acc1 = {0.f,0.f,0.f,0.f};
        acc0 = __builtin_amdgcn_mfma_f32_16x16x32_bf16(ah0, bh, acc0, 0, 0, 0);
        acc0 = __builtin_amdgcn_mfma_f32_16x16x32_bf16(ah0, bl, acc0, 0, 0, 0);
        acc0 = __builtin_amdgcn_mfma_f32_16x16x32_bf16(al0, bh, acc0, 0, 0, 0);
        acc1 = __builtin_amdgcn_mfma_f32_16x16x32_bf16(ah1, bh, acc1, 0, 0, 0);
        acc1 = __builtin_amdgcn_mfma_f32_16x16x32_bf16(ah1, bl, acc1, 0, 0, 0);
        acc1 = __builtin_amdgcn_mfma_f32_16x16x32_bf16(al1, bh, acc1, 0, 0, 0);
        const int n = nt * 16 + lr;
        #pragma unroll
        for (int r = 0; r < 4; ++r) {
            {
                const float d2 = fmaf(-2.f, acc0[r], cn);
                const bool lt1 = d2 < b1[r], lt2 = d2 < b2[r];
                b2[r] = lt1 ? b1[r] : (lt2 ? d2 : b2[r]);
                b1[r] = lt1 ? d2 : b1[r];
                i1[r] = lt1 ? n  : i1[r];
            }
            {
                const float d2 = fmaf(-2.f, acc1[r], cn);
                const bool lt1 = d2 < b1[4+r], lt2 = d2 < b2[4+r];
                b2[4+r] = lt1 ? b1[4+r] : (lt2 ? d2 : b2[4+r]);
                b1[4+r] = lt1 ? d2 : b1[4+r];
                i1[4+r] = lt1 ? n  : i1[4+r];
            }
        }
    }
    // merge top-2 across the 16 n-lanes of each group
    #pragma unroll
    for (int mk = 1; mk < 16; mk <<= 1) {
        #pragma unroll
        for (int s = 0; s < 8; ++s) {
            const float ob1 = __shfl_xor(b1[s], mk);
            const int   oi1 = __shfl_xor(i1[s], mk);
            const float ob2 = __shfl_xor(b2[s], mk);
            const bool take = (ob1 < b1[s]) || (ob1 == b1[s] && oi1 < i1[s]);
            const float loser = take ? b1[s] : ob1;
            b1[s] = take ? ob1 : b1[s];
            i1[s] = take ? oi1 : i1[s];
            b2[s] = fminf(fminf(b2[s], ob2), loser);
        }
    }
    #pragma unroll
    for (int s = 0; s < 8; ++s) {
        if (lr == s) {
            const int tokW = (s >> 2) * 16 + lg * 4 + (s & 3);
            si[wv][tokW] = i1[s] | (((b2[s] - b1[s]) < TAU) ? 512 : 0);
        }
    }
    __syncthreads();

    // ---- phase 3: exact fp32 rescan of flagged tokens (in-wave cooperative) ----
    {
        const int v = si[wv][tok];
        unsigned long long m = __ballot(half == 0 && (v & 512));
        while (m) {
            const int j = __ffsll(m) - 1; m &= m - 1;
            float xfj[D_];
            #pragma unroll
            for (int d = 0; d < D_; ++d) xfj[d] = xsh[wv][j][d];   // broadcast
            float bb = 3.4e38f; int bi = 0;
            #pragma unroll
            for (int p = 0; p < 8; ++p) {
                const int c = l + 64 * p;
                const float* row = cb + (size_t)c * D_;
                float p0 = 0.f, p1 = 0.f, p2 = 0.f, p3 = 0.f;
                #pragma unroll
                for (int d = 0; d < D_; d += 4) {
                    p0 = fmaf(xfj[d],   row[d],   p0); p1 = fmaf(xfj[d+1], row[d+1], p1);
                    p2 = fmaf(xfj[d+2], row[d+2], p2); p3 = fmaf(xfj[d+3], row[d+3], p3);
                }
                const float dd = fmaf(-2.f, (p0 + p1) + (p2 + p3), cbn[c]);
                if (dd < bb) { bb = dd; bi = c; }
            }
            #pragma unroll
            for (int s = 1; s < 64; s <<= 1) {
                const float ob = __shfl_xor(bb, s); const int oi = __shfl_xor(bi, s);
                if (ob < bb || (ob == bb && oi < bi)) { bb = ob; bi = oi; }
            }
            if (l == j) si[wv][j] = bi;
        }
    }
    __syncthreads();
    const int myidx = si[wv][tok] & 511;

    // ---- phase 4: gather, loss, idx write, post conv ----
    float qv[D_];
    {
        const float4* qrow = (const float4*)(cb + (size_t)myidx * D_);
        #pragma unroll
        for (int d4 = 0; d4 < 8; ++d4) {
            const float4 t = qrow[d4];
            qv[4*d4+0] = t.x; qv[4*d4+1] = t.y; qv[4*d4+2] = t.z; qv[4*d4+3] = t.w;
        }
    }
    float lacc = 0.f;
    if (half == 0) {
        #pragma unroll
        for (int d = 0; d < D_; ++d) {
            const float df = qv[d] - xsh[wv][tok][d];
            lacc = fmaf(df, df, lacc);
        }
        out[IDX_OFF + T0 + tok] = (float)myidx;
    }
    lacc += __shfl_down(lacc, 16); lacc += __shfl_down(lacc, 8);
    lacc += __shfl_down(lacc, 4);  lacc += __shfl_down(lacc, 2);
    lacc += __shfl_down(lacc, 1);
    if (l == 0) lsum[wv] = lacc;

    float* obase = out + (size_t)b * (C_ * HW_) + hw0 + tok;
    #pragma unroll
    for (int i = 0; i < 16; ++i) {
        const int c = half * 16 + i;
        float a = pb[c];
        const float4* pr = (const float4*)(pw + c * D_);
        #pragma unroll
        for (int d4 = 0; d4 < 8; ++d4) {
            const float4 p4 = pr[d4];
            a = fmaf(qv[4*d4+0], p4.x, a); a = fmaf(qv[4*d4+1], p4.y, a);
            a = fmaf(qv[4*d4+2], p4.z, a); a = fmaf(qv[4*d4+3], p4.w, a);
        }
        obase[(size_t)c * HW_] = a;
    }

    __syncthreads();
    if (tid == 0)
        atomicAdd(out + LOSS_OFF, ((lsum[0] + lsum[1]) + (lsum[2] + lsum[3])) * (2.0f / (float)(NTOK * D_)));
}

// ---------- fallback (round-1 monolithic, correct at ~125 us) ----------
__global__ __launch_bounds__(256)
void vq_mono(const float* __restrict__ z,  const float* __restrict__ qw,
             const float* __restrict__ qb, const float* __restrict__ cb,
             const float* __restrict__ pw, const float* __restrict__ pb,
             float* __restrict__ out)
{
    __shared__ float cbn_s[K_];
    __shared__ float lsum[4];
    const int tid = threadIdx.x;
    for (int k = tid; k < K_; k += 256) {
        const float* row = cb + k * D_;
        float s = 0.f;
        #pragma unroll
        for (int d = 0; d < D_; ++d) s = fmaf(row[d], row[d], s);
        cbn_s[k] = s;
    }
    __syncthreads();
    const int token = blockIdx.x * 256 + tid;
    const int b = token >> 12, hw = token & (HW_ - 1);
    const float* zbase = z + (size_t)b * C_ * HW_ + hw;
    float zv[C_];
    #pragma unroll
    for (int c = 0; c < C_; ++c) zv[c] = zbase[(size_t)c * HW_];
    float xf[D_];
    #pragma unroll
    for (int d = 0; d < D_; ++d) {
        float a = qb[d];
        #pragma unroll
        for (int c = 0; c < C_; ++c) a = fmaf(zv[c], qw[d * C_ + c], a);
        xf[d] = a;
    }
    float best = 3.4e38f; int bi = 0;
    #pragma unroll 2
    for (int k = 0; k < K_; ++k) {
        const float* row = cb + k * D_;
        float p0 = 0.f, p1 = 0.f, p2 = 0.f, p3 = 0.f;
        #pragma unroll
        for (int d = 0; d < D_; d += 4) {
            p0 = fmaf(xf[d+0], row[d+0], p0); p1 = fmaf(xf[d+1], row[d+1], p1);
            p2 = fmaf(xf[d+2], row[d+2], p2); p3 = fmaf(xf[d+3], row[d+3], p3);
        }
        const float s = fmaf(-2.f, (p0+p1)+(p2+p3), cbn_s[k]);
        if (s < best) { best = s; bi = k; }
    }
    out[IDX_OFF + token] = (float)bi;
    const float* qrow = cb + (size_t)bi * D_;
    float qv[D_];
    #pragma unroll
    for (int d = 0; d < D_; ++d) qv[d] = qrow[d];
    float l = 0.f;
    #pragma unroll
    for (int d = 0; d < D_; ++d) { const float df = qv[d] - xf[d]; l = fmaf(df, df, l); }
    float* obase = out + (size_t)b * C_ * HW_ + hw;
    #pragma unroll
    for (int c = 0; c < C_; ++c) {
        float a = pb[c];
        #pragma unroll
        for (int d = 0; d < D_; ++d) a = fmaf(qv[d], pw[c * D_ + d], a);
        obase[(size_t)c * HW_] = a;
    }
    #pragma unroll
    for (int off = 32; off; off >>= 1) l += __shfl_down(l, off);
    const int wid = tid >> 6, lane = tid & 63;
    if (lane == 0) lsum[wid] = l;
    __syncthreads();
    if (tid == 0) {
        const float t = (lsum[0] + lsum[1]) + (lsum[2] + lsum[3]);
        atomicAdd(out + LOSS_OFF, t * (2.0f / (float)(NTOK * D_)));
    }
}

extern "C" void kernel_launch(void* const* d_in, const int* in_sizes, int n_in,
                              void* d_out, int out_size, void* d_ws, size_t ws_size,
                              hipStream_t stream) {
    (void)in_sizes; (void)n_in; (void)out_size;
    const float* z  = (const float*)d_in[0];
    const float* qw = (const float*)d_in[1];
    const float* qb = (const float*)d_in[2];
    const float* cb = (const float*)d_in[3];
    const float* pw = (const float*)d_in[4];
    const float* pb = (const float*)d_in[5];
    float* out = (float*)d_out;

    hipMemsetAsync((char*)d_out + (size_t)LOSS_OFF * sizeof(float), 0, sizeof(float), stream);

    if (ws_size < (size_t)WS_NEEDED) {
        vq_mono<<<NTOK / 256, 256, 0, stream>>>(z, qw, qb, cb, pw, pb, out);
        return;
    }
    char* ws = (char*)d_ws;
    float*          cbn = (float*)(ws + WS_CBN);
    unsigned short* cbh = (unsigned short*)(ws + WS_CBH);
    unsigned short* cbl = (unsigned short*)(ws + WS_CBL);

    prep_cb<<<2, 256, 0, stream>>>(cb, cbn, cbh, cbl);
    vq_fused<<<NTOK / 128, 256, 0, stream>>>(z, qw, qb, cb, pw, pb, cbh, cbl, cbn, out);
}